// Round 5
// baseline (10801.571 us; speedup 1.0000x reference)
//
#include <hip/hip_runtime.h>
#include <hip/hip_bf16.h>

#define UNIT 20
#define HID 36
#define G4 144      // 4*HID
#define INW 80      // 4*UNIT
#define NCLS 3
#define TT 40960
#define SS 2048     // TT/UNIT
#define BB 512

__device__ __forceinline__ float exp2_hw(float x){ float r; asm("v_exp_f32 %0, %1" : "=v"(r) : "v"(x)); return r; }
__device__ __forceinline__ float rcp_hw(float x){ float r; asm("v_rcp_f32 %0, %1" : "=v"(r) : "v"(x)); return r; }
__device__ __forceinline__ float sigm_hw(float x){ return rcp_hw(1.f + exp2_hw(-1.4426950408889634f * x)); }
__device__ __forceinline__ float tanh_hw(float x){ return 1.f - 2.f * rcp_hw(1.f + exp2_hw(2.8853900817779268f * x)); }
__device__ __forceinline__ float rl(float v, int l){
    return __uint_as_float(__builtin_amdgcn_readlane(__float_as_uint(v), l));
}

// ---------------- kernel 1: input projection, LDS-free ----------------
// Block = 576 threads = 4 steps x 144 gate rows. x reads are wave-uniform
// (whole wave shares a timestep) -> scalar s_load path; weights in VGPRs.
__global__ __launch_bounds__(576)
void lstm_proj(const float* __restrict__ x, const float* __restrict__ W_ih,
               const float* __restrict__ b_ih, const float* __restrict__ b_hh,
               float* __restrict__ xw, int s0, int cnt, int nseq)
{
    const int bid = blockIdx.x;
    const int r   = bid % nseq;
    const int b   = bid / nseq;
    const int t   = threadIdx.x;
    const int so  = t / G4;          // 0..3: step sub-offset
    const int row = t - so * G4;     // 0..143: gate row
    const int base_local = r * 128;
    const int mysteps = min(128, cnt - base_local);

    float wih[INW];
    const float4* wr = (const float4*)(W_ih + (size_t)row * INW);
    #pragma unroll
    for (int q = 0; q < INW/4; ++q) {
        float4 v = wr[q];
        wih[4*q+0]=v.x; wih[4*q+1]=v.y; wih[4*q+2]=v.z; wih[4*q+3]=v.w;
    }
    const float bias = b_ih[row] + b_hh[row];
    const float* xb = x + (size_t)b * 4 * TT;

    for (int sub = so; sub < mysteps; sub += 4) {
        const int sg = s0 + base_local + sub;     // absolute step (wave-uniform mostly)
        float a0 = bias, a1 = 0.f, a2 = 0.f, a3 = 0.f;
        #pragma unroll
        for (int c = 0; c < 4; ++c) {
            const float* xs = xb + (size_t)c*TT + (size_t)sg*UNIT;
            #pragma unroll
            for (int q = 0; q < UNIT; q += 4) {
                a0 += xs[q+0] * wih[c*UNIT+q+0];
                a1 += xs[q+1] * wih[c*UNIT+q+1];
                a2 += xs[q+2] * wih[c*UNIT+q+2];
                a3 += xs[q+3] * wih[c*UNIT+q+3];
            }
        }
        xw[((size_t)(base_local + sub) * BB + b) * G4 + row] = (a0+a1)+(a2+a3);
    }
}

// ---------------- kernel 2: barrier-free recurrence (unchanged from R3) ----------------
__global__ __launch_bounds__(256)
void lstm_recur(const float* __restrict__ xw, const float* __restrict__ h0,
                const float* __restrict__ c0, const float* __restrict__ W_hh,
                const float* __restrict__ fc1_w, const float* __restrict__ fc1_b,
                const float* __restrict__ fc2_w, const float* __restrict__ fc2_b,
                float* __restrict__ state, float* __restrict__ out, int s0, int cnt)
{
    const int wid  = threadIdx.x >> 6;
    const int lane = threadIdx.x & 63;
    const int b    = blockIdx.x * 4 + wid;
    const int jj   = (lane < HID) ? lane : 0;

    float wreg[G4];
    #pragma unroll
    for (int g = 0; g < 4; ++g) {
        const float* wr = W_hh + (size_t)(g*HID + jj) * HID;
        #pragma unroll
        for (int q = 0; q < HID; ++q) wreg[g*HID + q] = wr[q];
    }

    float hval, cval;
    if (s0 == 0) { hval = h0[b*HID + jj];    cval = c0[b*HID + jj]; }
    else         { hval = state[b*HID + jj]; cval = state[BB*HID + b*HID + jj]; }

    float hs[HID];
    #pragma unroll
    for (int q = 0; q < HID; ++q) hs[q] = rl(hval, q);

    const float*  xp     = xw + (size_t)b * G4 + jj;
    const size_t  STRIDE = (size_t)BB * G4;

    float qa[8][4], qb[8][4];

#define LOADBANK(dst, base) { \
    _Pragma("unroll") for (int u = 0; u < 8; ++u) { \
        int ss = (base) + u; \
        const float* p = xp + (size_t)((ss < cnt) ? ss : 0) * STRIDE; \
        _Pragma("unroll") for (int g = 0; g < 4; ++g) dst[u][g] = p[g*HID]; \
    } }

#define DOSTEP(bk, u) { \
    float ai = bk[u][0], af = bk[u][1], ag = bk[u][2], ao = bk[u][3]; \
    _Pragma("unroll") for (int q = 0; q < HID; ++q) { \
        ai += hs[q] * wreg[q]; \
        af += hs[q] * wreg[HID   + q]; \
        ag += hs[q] * wreg[2*HID + q]; \
        ao += hs[q] * wreg[3*HID + q]; \
    } \
    float gi = sigm_hw(ai), gf = sigm_hw(af), gg = tanh_hw(ag), go = sigm_hw(ao); \
    cval = gf * cval + gi * gg; \
    hval = go * tanh_hw(cval); \
    _Pragma("unroll") for (int q = 0; q < HID; ++q) hs[q] = rl(hval, q); }

    LOADBANK(qa, 0);
    for (int s8 = 0; s8 < cnt; s8 += 16) {
        LOADBANK(qb, s8 + 8);
        DOSTEP(qa,0) DOSTEP(qa,1) DOSTEP(qa,2) DOSTEP(qa,3)
        DOSTEP(qa,4) DOSTEP(qa,5) DOSTEP(qa,6) DOSTEP(qa,7)
        LOADBANK(qa, s8 + 16);
        DOSTEP(qb,0) DOSTEP(qb,1) DOSTEP(qb,2) DOSTEP(qb,3)
        DOSTEP(qb,4) DOSTEP(qb,5) DOSTEP(qb,6) DOSTEP(qb,7)
    }
#undef LOADBANK
#undef DOSTEP

    if (s0 + cnt == SS) {
        float a1 = 0.f;
        if (lane < 16) {
            a1 = fc1_b[lane];
            #pragma unroll
            for (int k = 0; k < HID; ++k) a1 += hs[k] * fc1_w[lane*HID + k];
            a1 = fmaxf(a1, 0.f);
        }
        float f1[16];
        #pragma unroll
        for (int k = 0; k < 16; ++k) f1[k] = rl(a1, k);
        if (lane < NCLS) {
            float a2 = fc2_b[lane];
            #pragma unroll
            for (int k = 0; k < 16; ++k) a2 += f1[k] * fc2_w[lane*16 + k];
            out[b*NCLS + lane] = a2;
        }
    } else {
        if (lane < HID) {
            state[b*HID + lane]          = hval;
            state[BB*HID + b*HID + lane] = cval;
        }
    }
}

// ---------------- fallback (R1 fused kernel) for undersized workspace ----------------
__global__ __launch_bounds__(192)
void lstm_fused(const float* __restrict__ x, const float* __restrict__ h0,
                const float* __restrict__ c0, const float* __restrict__ W_ih,
                const float* __restrict__ W_hh, const float* __restrict__ b_ih,
                const float* __restrict__ b_hh, const float* __restrict__ fc1_w,
                const float* __restrict__ fc1_b, const float* __restrict__ fc2_w,
                const float* __restrict__ fc2_b, float* __restrict__ out)
{
    const int b = blockIdx.x;
    const int t = threadIdx.x;
    __shared__ __align__(16) float xin[16][INW];
    __shared__ __align__(16) float xwl[16][G4];
    __shared__ __align__(16) float h_s[HID];
    __shared__ __align__(16) float g_s[G4];
    float wih[INW]; float whh[HID];
    float bias = 0.f, K = 0.f, Aa = 0.f, Bb = 0.f;
    if (t < G4) {
        const float4* wr = (const float4*)(W_ih + t * INW);
        #pragma unroll
        for (int i = 0; i < INW/4; ++i) { float4 v = wr[i]; wih[4*i]=v.x; wih[4*i+1]=v.y; wih[4*i+2]=v.z; wih[4*i+3]=v.w; }
        const float4* hr = (const float4*)(W_hh + t * HID);
        #pragma unroll
        for (int j = 0; j < HID/4; ++j) { float4 v = hr[j]; whh[4*j]=v.x; whh[4*j+1]=v.y; whh[4*j+2]=v.z; whh[4*j+3]=v.w; }
        bias = b_ih[t] + b_hh[t];
        const bool tnh = (t >= 2*HID && t < 3*HID);
        K  = tnh ?  2.8853900817779268f : -1.4426950408889634f;
        Aa = tnh ?  1.f : 0.f;
        Bb = tnh ? -2.f : 1.f;
    }
    float c = 0.f;
    if (t < HID) { c = c0[b*HID + t]; h_s[t] = h0[b*HID + t]; }
    __syncthreads();
    const float* xb = x + (size_t)b * 4 * TT;
    for (int ck = 0; ck < SS/16; ++ck) {
        const int base = ck * 16 * UNIT;
        for (int j = t; j < 4*16*UNIT; j += 192) {
            int chn = j / (16*UNIT); int r = j - chn*(16*UNIT);
            xin[r/UNIT][chn*UNIT + (r%UNIT)] = xb[chn*TT + base + r];
        }
        __syncthreads();
        if (t < G4) {
            for (int s = 0; s < 16; ++s) {
                const float4* xv = (const float4*)xin[s];
                float a0 = bias, a1 = 0.f, a2 = 0.f, a3 = 0.f;
                #pragma unroll
                for (int i = 0; i < INW/4; ++i) {
                    float4 v = xv[i];
                    a0 += v.x*wih[4*i]; a1 += v.y*wih[4*i+1]; a2 += v.z*wih[4*i+2]; a3 += v.w*wih[4*i+3];
                }
                xwl[s][t] = (a0+a1)+(a2+a3);
            }
        }
        __syncthreads();
        for (int s = 0; s < 16; ++s) {
            if (t < G4) {
                const float4* hv = (const float4*)h_s;
                float a0 = xwl[s][t], a1 = 0.f, a2 = 0.f, a3 = 0.f;
                #pragma unroll
                for (int j = 0; j < HID/4; ++j) {
                    float4 v = hv[j];
                    a0 += v.x*whh[4*j]; a1 += v.y*whh[4*j+1]; a2 += v.z*whh[4*j+2]; a3 += v.w*whh[4*j+3];
                }
                float acc = (a0+a1)+(a2+a3);
                g_s[t] = Aa + Bb * rcp_hw(1.f + exp2_hw(K * acc));
            }
            __syncthreads();
            if (t < HID) {
                float ig=g_s[t], fg=g_s[HID+t], gg=g_s[2*HID+t], og=g_s[3*HID+t];
                c = fg*c + ig*gg;
                h_s[t] = og * tanh_hw(c);
            }
            __syncthreads();
        }
    }
    if (t < 16) {
        float a = fc1_b[t];
        #pragma unroll
        for (int j = 0; j < HID; ++j) a += h_s[j]*fc1_w[t*HID+j];
        g_s[t] = fmaxf(a, 0.f);
    }
    __syncthreads();
    if (t < NCLS) {
        float a = fc2_b[t];
        #pragma unroll
        for (int j = 0; j < 16; ++j) a += g_s[j]*fc2_w[t*16+j];
        out[b*NCLS + t] = a;
    }
}

extern "C" void kernel_launch(void* const* d_in, const int* in_sizes, int n_in,
                              void* d_out, int out_size, void* d_ws, size_t ws_size,
                              hipStream_t stream) {
    const float* x     = (const float*)d_in[0];
    const float* h0    = (const float*)d_in[1];
    const float* c0    = (const float*)d_in[2];
    const float* W_ih  = (const float*)d_in[3];
    const float* W_hh  = (const float*)d_in[4];
    const float* b_ih  = (const float*)d_in[5];
    const float* b_hh  = (const float*)d_in[6];
    const float* fc1_w = (const float*)d_in[7];
    const float* fc1_b = (const float*)d_in[8];
    const float* fc2_w = (const float*)d_in[9];
    const float* fc2_b = (const float*)d_in[10];
    float* out = (float*)d_out;

    // workspace layout: [h state 512*36][c state 512*36][xw chunk buffer]
    const size_t state_floats = (size_t)BB * HID * 2;
    long cap = (long)(ws_size / 4) - (long)state_floats;
    long sc  = (cap > 0) ? cap / ((long)BB * G4) : 0;
    int  SC  = (int)((sc > SS) ? SS : sc) & ~15;

    if (SC < 16) {
        // workspace too small — proven fused fallback
        lstm_fused<<<BB, 192, 0, stream>>>(x, h0, c0, W_ih, W_hh, b_ih, b_hh,
                                           fc1_w, fc1_b, fc2_w, fc2_b, out);
        return;
    }

    float* state = (float*)d_ws;
    float* xwbuf = state + state_floats;

    for (int s0 = 0; s0 < SS; s0 += SC) {
        int cnt = SS - s0; if (cnt > SC) cnt = SC;
        int nseq = (cnt + 127) / 128;
        lstm_proj<<<BB * nseq, 576, 0, stream>>>(x, W_ih, b_ih, b_hh, xwbuf, s0, cnt, nseq);
        lstm_recur<<<BB / 4, 256, 0, stream>>>(xwbuf, h0, c0, W_hh,
                                               fc1_w, fc1_b, fc2_w, fc2_b,
                                               state, out, s0, cnt);
    }
}

// Round 6
// 5401.176 us; speedup vs baseline: 1.9999x; 1.9999x over previous
//
#include <hip/hip_runtime.h>
#include <hip/hip_bf16.h>

#define UNIT 20
#define HID 36
#define G4 144      // 4*HID
#define INW 80      // 4*UNIT
#define NCLS 3
#define TT 40960
#define SS 2048     // TT/UNIT
#define BB 512

__device__ __forceinline__ float exp2_hw(float x){ float r; asm("v_exp_f32 %0, %1" : "=v"(r) : "v"(x)); return r; }
__device__ __forceinline__ float rcp_hw(float x){ float r; asm("v_rcp_f32 %0, %1" : "=v"(r) : "v"(x)); return r; }
__device__ __forceinline__ float sigm_hw(float x){ return rcp_hw(1.f + exp2_hw(-1.4426950408889634f * x)); }
__device__ __forceinline__ float tanh_hw(float x){ return 1.f - 2.f * rcp_hw(1.f + exp2_hw(2.8853900817779268f * x)); }
__device__ __forceinline__ float rl(float v, int l){
    return __uint_as_float(__builtin_amdgcn_readlane(__float_as_uint(v), l));
}

// ---------------- kernel 1: input projection, transposed mapping ----------------
// Block = 256 thr = 4 waves; lane = timestep (2 steps/lane -> 512 steps/block).
// x lives in VGPRs (160/lane); W_ih broadcast from LDS (same-addr b128 = HW
// broadcast, conflict-free). One b128 feeds 8 FMAs -> LDS no longer the pipe.
__global__ __launch_bounds__(256)
void lstm_proj(const float* __restrict__ x, const float* __restrict__ W_ih,
               const float* __restrict__ b_ih, const float* __restrict__ b_hh,
               float* __restrict__ xw, int s0, int cnt, int nseq)
{
    const int bid = blockIdx.x;
    const int r   = bid % nseq;        // 512-step slab within chunk
    const int b   = bid / nseq;
    const int tid = threadIdx.x;
    const int w   = tid >> 6;
    const int l   = tid & 63;

    __shared__ __align__(16) float Wl[G4 * INW];   // 45 KB
    __shared__ float bl[G4];

    for (int i = 4*tid; i < G4*INW; i += 4*256)
        *(float4*)&Wl[i] = *(const float4*)&W_ih[i];
    for (int i = tid; i < G4; i += 256) bl[i] = b_ih[i] + b_hh[i];
    __syncthreads();

    const int s_loc0 = r*512 + w*128 + l;          // chunk-local step, k=0
    const int s_loc1 = s_loc0 + 64;                // k=1
    const bool v0 = s_loc0 < cnt;
    const bool v1 = s_loc1 < cnt;
    const int sg0 = s0 + (v0 ? s_loc0 : 0);        // absolute step (clamped)
    const int sg1 = s0 + (v1 ? s_loc1 : 0);

    const float* xb = x + (size_t)b * 4 * TT;
    float xr0[INW], xr1[INW];
    #pragma unroll
    for (int c = 0; c < 4; ++c) {
        #pragma unroll
        for (int q = 0; q < 5; ++q) {              // 80B*s is 16B-aligned
            float4 a = *(const float4*)(xb + (size_t)c*TT + (size_t)sg0*UNIT + 4*q);
            float4 d = *(const float4*)(xb + (size_t)c*TT + (size_t)sg1*UNIT + 4*q);
            xr0[c*UNIT+4*q+0]=a.x; xr0[c*UNIT+4*q+1]=a.y; xr0[c*UNIT+4*q+2]=a.z; xr0[c*UNIT+4*q+3]=a.w;
            xr1[c*UNIT+4*q+0]=d.x; xr1[c*UNIT+4*q+1]=d.y; xr1[c*UNIT+4*q+2]=d.z; xr1[c*UNIT+4*q+3]=d.w;
        }
    }

    float* out0 = xw + ((size_t)s_loc0 * BB + b) * G4;
    float* out1 = xw + ((size_t)s_loc1 * BB + b) * G4;

    for (int rg = 0; rg < G4/4; ++rg) {
        float o0[4], o1[4];
        #pragma unroll
        for (int j = 0; j < 4; ++j) {
            const int rr = rg*4 + j;
            const float* wp = &Wl[rr * INW];
            const float bs = bl[rr];
            float a0=bs, a1=0.f, a2=0.f, a3=0.f;
            float c0=bs, c1=0.f, c2=0.f, c3=0.f;
            #pragma unroll
            for (int q = 0; q < 20; ++q) {
                float4 wv = *(const float4*)&wp[4*q];      // broadcast read
                a0 += wv.x*xr0[4*q+0]; a1 += wv.y*xr0[4*q+1];
                a2 += wv.z*xr0[4*q+2]; a3 += wv.w*xr0[4*q+3];
                c0 += wv.x*xr1[4*q+0]; c1 += wv.y*xr1[4*q+1];
                c2 += wv.z*xr1[4*q+2]; c3 += wv.w*xr1[4*q+3];
            }
            o0[j] = (a0+a1)+(a2+a3);
            o1[j] = (c0+c1)+(c2+c3);
        }
        if (v0) *(float4*)(out0 + rg*4) = make_float4(o0[0],o0[1],o0[2],o0[3]);
        if (v1) *(float4*)(out1 + rg*4) = make_float4(o1[0],o1[1],o1[2],o1[3]);
    }
}

// ---------------- kernel 2: barrier-free recurrence (unchanged, proven R3) ----------------
__global__ __launch_bounds__(256)
void lstm_recur(const float* __restrict__ xw, const float* __restrict__ h0,
                const float* __restrict__ c0, const float* __restrict__ W_hh,
                const float* __restrict__ fc1_w, const float* __restrict__ fc1_b,
                const float* __restrict__ fc2_w, const float* __restrict__ fc2_b,
                float* __restrict__ state, float* __restrict__ out, int s0, int cnt)
{
    const int wid  = threadIdx.x >> 6;
    const int lane = threadIdx.x & 63;
    const int b    = blockIdx.x * 4 + wid;
    const int jj   = (lane < HID) ? lane : 0;

    float wreg[G4];
    #pragma unroll
    for (int g = 0; g < 4; ++g) {
        const float* wr = W_hh + (size_t)(g*HID + jj) * HID;
        #pragma unroll
        for (int q = 0; q < HID; ++q) wreg[g*HID + q] = wr[q];
    }

    float hval, cval;
    if (s0 == 0) { hval = h0[b*HID + jj];    cval = c0[b*HID + jj]; }
    else         { hval = state[b*HID + jj]; cval = state[BB*HID + b*HID + jj]; }

    float hs[HID];
    #pragma unroll
    for (int q = 0; q < HID; ++q) hs[q] = rl(hval, q);

    const float*  xp     = xw + (size_t)b * G4 + jj;
    const size_t  STRIDE = (size_t)BB * G4;

    float qa[8][4], qb[8][4];

#define LOADBANK(dst, base) { \
    _Pragma("unroll") for (int u = 0; u < 8; ++u) { \
        int ss = (base) + u; \
        const float* p = xp + (size_t)((ss < cnt) ? ss : 0) * STRIDE; \
        _Pragma("unroll") for (int g = 0; g < 4; ++g) dst[u][g] = p[g*HID]; \
    } }

#define DOSTEP(bk, u) { \
    float ai = bk[u][0], af = bk[u][1], ag = bk[u][2], ao = bk[u][3]; \
    _Pragma("unroll") for (int q = 0; q < HID; ++q) { \
        ai += hs[q] * wreg[q]; \
        af += hs[q] * wreg[HID   + q]; \
        ag += hs[q] * wreg[2*HID + q]; \
        ao += hs[q] * wreg[3*HID + q]; \
    } \
    float gi = sigm_hw(ai), gf = sigm_hw(af), gg = tanh_hw(ag), go = sigm_hw(ao); \
    cval = gf * cval + gi * gg; \
    hval = go * tanh_hw(cval); \
    _Pragma("unroll") for (int q = 0; q < HID; ++q) hs[q] = rl(hval, q); }

    LOADBANK(qa, 0);
    for (int s8 = 0; s8 < cnt; s8 += 16) {
        LOADBANK(qb, s8 + 8);
        DOSTEP(qa,0) DOSTEP(qa,1) DOSTEP(qa,2) DOSTEP(qa,3)
        DOSTEP(qa,4) DOSTEP(qa,5) DOSTEP(qa,6) DOSTEP(qa,7)
        LOADBANK(qa, s8 + 16);
        DOSTEP(qb,0) DOSTEP(qb,1) DOSTEP(qb,2) DOSTEP(qb,3)
        DOSTEP(qb,4) DOSTEP(qb,5) DOSTEP(qb,6) DOSTEP(qb,7)
    }
#undef LOADBANK
#undef DOSTEP

    if (s0 + cnt == SS) {
        float a1 = 0.f;
        if (lane < 16) {
            a1 = fc1_b[lane];
            #pragma unroll
            for (int k = 0; k < HID; ++k) a1 += hs[k] * fc1_w[lane*HID + k];
            a1 = fmaxf(a1, 0.f);
        }
        float f1[16];
        #pragma unroll
        for (int k = 0; k < 16; ++k) f1[k] = rl(a1, k);
        if (lane < NCLS) {
            float a2 = fc2_b[lane];
            #pragma unroll
            for (int k = 0; k < 16; ++k) a2 += f1[k] * fc2_w[lane*16 + k];
            out[b*NCLS + lane] = a2;
        }
    } else {
        if (lane < HID) {
            state[b*HID + lane]          = hval;
            state[BB*HID + b*HID + lane] = cval;
        }
    }
}

// ---------------- fallback (R1 fused kernel) for undersized workspace ----------------
__global__ __launch_bounds__(192)
void lstm_fused(const float* __restrict__ x, const float* __restrict__ h0,
                const float* __restrict__ c0, const float* __restrict__ W_ih,
                const float* __restrict__ W_hh, const float* __restrict__ b_ih,
                const float* __restrict__ b_hh, const float* __restrict__ fc1_w,
                const float* __restrict__ fc1_b, const float* __restrict__ fc2_w,
                const float* __restrict__ fc2_b, float* __restrict__ out)
{
    const int b = blockIdx.x;
    const int t = threadIdx.x;
    __shared__ __align__(16) float xin[16][INW];
    __shared__ __align__(16) float xwl[16][G4];
    __shared__ __align__(16) float h_s[HID];
    __shared__ __align__(16) float g_s[G4];
    float wih[INW]; float whh[HID];
    float bias = 0.f, K = 0.f, Aa = 0.f, Bb = 0.f;
    if (t < G4) {
        const float4* wr = (const float4*)(W_ih + t * INW);
        #pragma unroll
        for (int i = 0; i < INW/4; ++i) { float4 v = wr[i]; wih[4*i]=v.x; wih[4*i+1]=v.y; wih[4*i+2]=v.z; wih[4*i+3]=v.w; }
        const float4* hr = (const float4*)(W_hh + t * HID);
        #pragma unroll
        for (int j = 0; j < HID/4; ++j) { float4 v = hr[j]; whh[4*j]=v.x; whh[4*j+1]=v.y; whh[4*j+2]=v.z; whh[4*j+3]=v.w; }
        bias = b_ih[t] + b_hh[t];
        const bool tnh = (t >= 2*HID && t < 3*HID);
        K  = tnh ?  2.8853900817779268f : -1.4426950408889634f;
        Aa = tnh ?  1.f : 0.f;
        Bb = tnh ? -2.f : 1.f;
    }
    float c = 0.f;
    if (t < HID) { c = c0[b*HID + t]; h_s[t] = h0[b*HID + t]; }
    __syncthreads();
    const float* xb = x + (size_t)b * 4 * TT;
    for (int ck = 0; ck < SS/16; ++ck) {
        const int base = ck * 16 * UNIT;
        for (int j = t; j < 4*16*UNIT; j += 192) {
            int chn = j / (16*UNIT); int r = j - chn*(16*UNIT);
            xin[r/UNIT][chn*UNIT + (r%UNIT)] = xb[chn*TT + base + r];
        }
        __syncthreads();
        if (t < G4) {
            for (int s = 0; s < 16; ++s) {
                const float4* xv = (const float4*)xin[s];
                float a0 = bias, a1 = 0.f, a2 = 0.f, a3 = 0.f;
                #pragma unroll
                for (int i = 0; i < INW/4; ++i) {
                    float4 v = xv[i];
                    a0 += v.x*wih[4*i]; a1 += v.y*wih[4*i+1]; a2 += v.z*wih[4*i+2]; a3 += v.w*wih[4*i+3];
                }
                xwl[s][t] = (a0+a1)+(a2+a3);
            }
        }
        __syncthreads();
        for (int s = 0; s < 16; ++s) {
            if (t < G4) {
                const float4* hv = (const float4*)h_s;
                float a0 = xwl[s][t], a1 = 0.f, a2 = 0.f, a3 = 0.f;
                #pragma unroll
                for (int j = 0; j < HID/4; ++j) {
                    float4 v = hv[j];
                    a0 += v.x*whh[4*j]; a1 += v.y*whh[4*j+1]; a2 += v.z*whh[4*j+2]; a3 += v.w*whh[4*j+3];
                }
                float acc = (a0+a1)+(a2+a3);
                g_s[t] = Aa + Bb * rcp_hw(1.f + exp2_hw(K * acc));
            }
            __syncthreads();
            if (t < HID) {
                float ig=g_s[t], fg=g_s[HID+t], gg=g_s[2*HID+t], og=g_s[3*HID+t];
                c = fg*c + ig*gg;
                h_s[t] = og * tanh_hw(c);
            }
            __syncthreads();
        }
    }
    if (t < 16) {
        float a = fc1_b[t];
        #pragma unroll
        for (int j = 0; j < HID; ++j) a += h_s[j]*fc1_w[t*HID+j];
        g_s[t] = fmaxf(a, 0.f);
    }
    __syncthreads();
    if (t < NCLS) {
        float a = fc2_b[t];
        #pragma unroll
        for (int j = 0; j < 16; ++j) a += g_s[j]*fc2_w[t*16+j];
        out[b*NCLS + t] = a;
    }
}

extern "C" void kernel_launch(void* const* d_in, const int* in_sizes, int n_in,
                              void* d_out, int out_size, void* d_ws, size_t ws_size,
                              hipStream_t stream) {
    const float* x     = (const float*)d_in[0];
    const float* h0    = (const float*)d_in[1];
    const float* c0    = (const float*)d_in[2];
    const float* W_ih  = (const float*)d_in[3];
    const float* W_hh  = (const float*)d_in[4];
    const float* b_ih  = (const float*)d_in[5];
    const float* b_hh  = (const float*)d_in[6];
    const float* fc1_w = (const float*)d_in[7];
    const float* fc1_b = (const float*)d_in[8];
    const float* fc2_w = (const float*)d_in[9];
    const float* fc2_b = (const float*)d_in[10];
    float* out = (float*)d_out;

    // workspace layout: [h state 512*36][c state 512*36][xw chunk buffer]
    const size_t state_floats = (size_t)BB * HID * 2;
    long cap = (long)(ws_size / 4) - (long)state_floats;
    long sc  = (cap > 0) ? cap / ((long)BB * G4) : 0;
    int  SC  = (int)((sc > SS) ? SS : sc) & ~15;

    if (SC < 16) {
        // workspace too small — proven fused fallback
        lstm_fused<<<BB, 192, 0, stream>>>(x, h0, c0, W_ih, W_hh, b_ih, b_hh,
                                           fc1_w, fc1_b, fc2_w, fc2_b, out);
        return;
    }

    float* state = (float*)d_ws;
    float* xwbuf = state + state_floats;

    for (int s0 = 0; s0 < SS; s0 += SC) {
        int cnt = SS - s0; if (cnt > SC) cnt = SC;
        int nseq = (cnt + 511) / 512;
        lstm_proj<<<BB * nseq, 256, 0, stream>>>(x, W_ih, b_ih, b_hh, xwbuf, s0, cnt, nseq);
        lstm_recur<<<BB / 4, 256, 0, stream>>>(xwbuf, h0, c0, W_hh,
                                               fc1_w, fc1_b, fc2_w, fc2_b,
                                               state, out, s0, cnt);
    }
}

// Round 7
// 1268.144 us; speedup vs baseline: 8.5176x; 4.2591x over previous
//
#include <hip/hip_runtime.h>
#include <hip/hip_bf16.h>

#define UNIT 20
#define HID 36
#define G4 144      // 4*HID
#define INW 80      // 4*UNIT
#define NCLS 3
#define TT 40960
#define SS 2048     // TT/UNIT
#define BB 512
#define PAD 16      // xw slop steps so prefetch needs no clamp

typedef float v2f __attribute__((ext_vector_type(2)));

__device__ __forceinline__ float exp2_hw(float x){ float r; asm("v_exp_f32 %0, %1" : "=v"(r) : "v"(x)); return r; }
__device__ __forceinline__ float rcp_hw(float x){ float r; asm("v_rcp_f32 %0, %1" : "=v"(r) : "v"(x)); return r; }
__device__ __forceinline__ float sigm_hw(float x){ return rcp_hw(1.f + exp2_hw(-1.4426950408889634f * x)); }
__device__ __forceinline__ float tanh_hw(float x){ return 1.f - 2.f * rcp_hw(1.f + exp2_hw(2.8853900817779268f * x)); }
__device__ __forceinline__ float rl(float v, int l){
    return __uint_as_float(__builtin_amdgcn_readlane(__float_as_uint(v), l));
}

// ---------------- kernel 1: input projection (R3 staging + 2-row pk compute) ----------------
// Block 192 thr / 1 batch. Threads 0..143: (pr = t%72, slot = t/72) own gate
// rows {pr, pr+72} as v2f and process steps of parity `slot`. Each x ds_read_b128
// now feeds 2 rows x 2 steps of the block -> LDS cost per step halves vs R3.
__global__ __launch_bounds__(192)
void lstm_proj2(const float* __restrict__ x, const float* __restrict__ W_ih,
                const float* __restrict__ b_ih, const float* __restrict__ b_hh,
                float* __restrict__ xw, int s0, int cnt, int nseq)
{
    const int bid = blockIdx.x;
    const int r   = bid % nseq;
    const int b   = bid / nseq;
    const int t   = threadIdx.x;
    const int base_local = r * 128;
    const int mysteps = min(128, cnt - base_local);
    const bool act = (t < 144);
    const int pr   = act ? (t % 72) : 0;
    const int slot = act ? (t / 72) : 0;

    __shared__ __align__(16) float xin[16][INW];

    v2f wpk[INW]; v2f bias2 = {0.f, 0.f};
    if (act) {
        const float* w0 = W_ih + (size_t)pr * INW;
        const float* w1 = W_ih + (size_t)(pr + 72) * INW;
        #pragma unroll
        for (int q = 0; q < INW; ++q) wpk[q] = (v2f){w0[q], w1[q]};
        bias2 = (v2f){b_ih[pr] + b_hh[pr], b_ih[pr+72] + b_hh[pr+72]};
    }
    const float* xb = x + (size_t)b * 4 * TT;

    for (int sub = 0; sub < mysteps; sub += 16) {
        const int sg = s0 + base_local + sub;
        __syncthreads();                       // xin safe to overwrite
        for (int j = t; j < 320; j += 192) {   // proven R3 coalesced staging
            int c = j / 80, q = j - c*80;
            float4 v = ((const float4*)(xb + (size_t)c*TT + (size_t)sg*UNIT))[q];
            int e = q*4; int sl = e / UNIT, u = e - sl*UNIT;
            *(float4*)&xin[sl][c*UNIT + u] = v;
        }
        __syncthreads();
        if (act) {
            for (int si = slot; si < 16; si += 2) {
                const float4* xv = (const float4*)xin[si];
                v2f a0 = bias2, a1 = {0.f,0.f}, a2 = {0.f,0.f}, a3 = {0.f,0.f};
                #pragma unroll
                for (int q = 0; q < 20; ++q) {
                    float4 v = xv[q];
                    a0 += v.x * wpk[4*q+0];
                    a1 += v.y * wpk[4*q+1];
                    a2 += v.z * wpk[4*q+2];
                    a3 += v.w * wpk[4*q+3];
                }
                v2f res = (a0 + a1) + (a2 + a3);
                size_t o = ((size_t)(base_local + sub + si) * BB + b) * G4;
                xw[o + pr]      = res[0];
                xw[o + pr + 72] = res[1];
            }
        }
    }
}

// ---------------- kernel 2: full-sequence recurrence, pk-FMA, no clamps ----------------
__global__ __launch_bounds__(256)
void lstm_recur_full(const float* __restrict__ xw, const float* __restrict__ h0,
                     const float* __restrict__ c0, const float* __restrict__ W_hh,
                     const float* __restrict__ fc1_w, const float* __restrict__ fc1_b,
                     const float* __restrict__ fc2_w, const float* __restrict__ fc2_b,
                     float* __restrict__ out)
{
    const int wid  = threadIdx.x >> 6;
    const int lane = threadIdx.x & 63;
    const int b    = blockIdx.x * 4 + wid;
    const int jj   = (lane < HID) ? lane : 0;

    // packed weights: wif[q] = {W_i[jj][q], W_f[jj][q]}, wgo[q] = {W_g[jj][q], W_o[jj][q]}
    v2f wif[HID], wgo[HID];
    #pragma unroll
    for (int q = 0; q < HID; ++q) {
        wif[q] = (v2f){ W_hh[(size_t)jj*HID + q],         W_hh[(size_t)(HID+jj)*HID + q] };
        wgo[q] = (v2f){ W_hh[(size_t)(2*HID+jj)*HID + q], W_hh[(size_t)(3*HID+jj)*HID + q] };
    }

    float hval = h0[b*HID + jj];
    float cval = c0[b*HID + jj];
    float hs[HID];
    #pragma unroll
    for (int q = 0; q < HID; ++q) hs[q] = rl(hval, q);

    const float*  xp     = xw + (size_t)b * G4 + jj;
    const size_t  STRIDE = (size_t)BB * G4;

    float qa[8][4], qb[8][4];

#define LOADBANK(dst, base) { \
    _Pragma("unroll") for (int u = 0; u < 8; ++u) { \
        const float* p = xp + (size_t)((base) + u) * STRIDE; \
        dst[u][0] = p[0]; dst[u][1] = p[HID]; dst[u][2] = p[2*HID]; dst[u][3] = p[3*HID]; \
    } }

#define DOSTEP(bk, u) { \
    v2f aifA = { bk[u][0], bk[u][1] }, aifB = {0.f,0.f}; \
    v2f agoA = { bk[u][2], bk[u][3] }, agoB = {0.f,0.f}; \
    _Pragma("unroll") for (int q = 0; q < HID; q += 2) { \
        aifA += hs[q]   * wif[q]; \
        agoA += hs[q]   * wgo[q]; \
        aifB += hs[q+1] * wif[q+1]; \
        agoB += hs[q+1] * wgo[q+1]; \
    } \
    v2f aif = aifA + aifB, ago = agoA + agoB; \
    float gi = sigm_hw(aif[0]), gf = sigm_hw(aif[1]); \
    float gg = tanh_hw(ago[0]), go = sigm_hw(ago[1]); \
    cval = gf * cval + gi * gg; \
    hval = go * tanh_hw(cval); \
    _Pragma("unroll") for (int q = 0; q < HID; ++q) hs[q] = rl(hval, q); }

    LOADBANK(qa, 0);
    for (int s8 = 0; s8 < SS; s8 += 16) {
        LOADBANK(qb, s8 + 8);
        DOSTEP(qa,0) DOSTEP(qa,1) DOSTEP(qa,2) DOSTEP(qa,3)
        DOSTEP(qa,4) DOSTEP(qa,5) DOSTEP(qa,6) DOSTEP(qa,7)
        LOADBANK(qa, s8 + 16);                 // reads into PAD slop at the tail
        DOSTEP(qb,0) DOSTEP(qb,1) DOSTEP(qb,2) DOSTEP(qb,3)
        DOSTEP(qb,4) DOSTEP(qb,5) DOSTEP(qb,6) DOSTEP(qb,7)
    }
#undef LOADBANK
#undef DOSTEP

    // classifier head, in-wave (hs holds final h, uniform)
    float a1 = 0.f;
    if (lane < 16) {
        a1 = fc1_b[lane];
        #pragma unroll
        for (int q = 0; q < HID; ++q) a1 += hs[q] * fc1_w[lane*HID + q];
        a1 = fmaxf(a1, 0.f);
    }
    float f1[16];
    #pragma unroll
    for (int q = 0; q < 16; ++q) f1[q] = rl(a1, q);
    if (lane < NCLS) {
        float a2 = fc2_b[lane];
        #pragma unroll
        for (int q = 0; q < 16; ++q) a2 += f1[q] * fc2_w[lane*16 + q];
        out[b*NCLS + lane] = a2;
    }
}

// ---------------- fallback: chunked recurrence (R3, proven, clamped) ----------------
__global__ __launch_bounds__(256)
void lstm_recur(const float* __restrict__ xw, const float* __restrict__ h0,
                const float* __restrict__ c0, const float* __restrict__ W_hh,
                const float* __restrict__ fc1_w, const float* __restrict__ fc1_b,
                const float* __restrict__ fc2_w, const float* __restrict__ fc2_b,
                float* __restrict__ state, float* __restrict__ out, int s0, int cnt)
{
    const int wid  = threadIdx.x >> 6;
    const int lane = threadIdx.x & 63;
    const int b    = blockIdx.x * 4 + wid;
    const int jj   = (lane < HID) ? lane : 0;

    float wreg[G4];
    #pragma unroll
    for (int g = 0; g < 4; ++g) {
        const float* wr = W_hh + (size_t)(g*HID + jj) * HID;
        #pragma unroll
        for (int q = 0; q < HID; ++q) wreg[g*HID + q] = wr[q];
    }

    float hval, cval;
    if (s0 == 0) { hval = h0[b*HID + jj];    cval = c0[b*HID + jj]; }
    else         { hval = state[b*HID + jj]; cval = state[BB*HID + b*HID + jj]; }

    float hs[HID];
    #pragma unroll
    for (int q = 0; q < HID; ++q) hs[q] = rl(hval, q);

    const float*  xp     = xw + (size_t)b * G4 + jj;
    const size_t  STRIDE = (size_t)BB * G4;

    float qa[8][4], qb[8][4];

#define LOADBANK(dst, base) { \
    _Pragma("unroll") for (int u = 0; u < 8; ++u) { \
        int ss = (base) + u; \
        const float* p = xp + (size_t)((ss < cnt) ? ss : 0) * STRIDE; \
        _Pragma("unroll") for (int g = 0; g < 4; ++g) dst[u][g] = p[g*HID]; \
    } }

#define DOSTEP(bk, u) { \
    float ai = bk[u][0], af = bk[u][1], ag = bk[u][2], ao = bk[u][3]; \
    _Pragma("unroll") for (int q = 0; q < HID; ++q) { \
        ai += hs[q] * wreg[q]; \
        af += hs[q] * wreg[HID   + q]; \
        ag += hs[q] * wreg[2*HID + q]; \
        ao += hs[q] * wreg[3*HID + q]; \
    } \
    float gi = sigm_hw(ai), gf = sigm_hw(af), gg = tanh_hw(ag), go = sigm_hw(ao); \
    cval = gf * cval + gi * gg; \
    hval = go * tanh_hw(cval); \
    _Pragma("unroll") for (int q = 0; q < HID; ++q) hs[q] = rl(hval, q); }

    LOADBANK(qa, 0);
    for (int s8 = 0; s8 < cnt; s8 += 16) {
        LOADBANK(qb, s8 + 8);
        DOSTEP(qa,0) DOSTEP(qa,1) DOSTEP(qa,2) DOSTEP(qa,3)
        DOSTEP(qa,4) DOSTEP(qa,5) DOSTEP(qa,6) DOSTEP(qa,7)
        LOADBANK(qa, s8 + 16);
        DOSTEP(qb,0) DOSTEP(qb,1) DOSTEP(qb,2) DOSTEP(qb,3)
        DOSTEP(qb,4) DOSTEP(qb,5) DOSTEP(qb,6) DOSTEP(qb,7)
    }
#undef LOADBANK
#undef DOSTEP

    if (s0 + cnt == SS) {
        float a1 = 0.f;
        if (lane < 16) {
            a1 = fc1_b[lane];
            #pragma unroll
            for (int k = 0; k < HID; ++k) a1 += hs[k] * fc1_w[lane*HID + k];
            a1 = fmaxf(a1, 0.f);
        }
        float f1[16];
        #pragma unroll
        for (int k = 0; k < 16; ++k) f1[k] = rl(a1, k);
        if (lane < NCLS) {
            float a2 = fc2_b[lane];
            #pragma unroll
            for (int k = 0; k < 16; ++k) a2 += f1[k] * fc2_w[lane*16 + k];
            out[b*NCLS + lane] = a2;
        }
    } else {
        if (lane < HID) {
            state[b*HID + lane]          = hval;
            state[BB*HID + b*HID + lane] = cval;
        }
    }
}

// ---------------- fallback (R1 fused kernel) for undersized workspace ----------------
__global__ __launch_bounds__(192)
void lstm_fused(const float* __restrict__ x, const float* __restrict__ h0,
                const float* __restrict__ c0, const float* __restrict__ W_ih,
                const float* __restrict__ W_hh, const float* __restrict__ b_ih,
                const float* __restrict__ b_hh, const float* __restrict__ fc1_w,
                const float* __restrict__ fc1_b, const float* __restrict__ fc2_w,
                const float* __restrict__ fc2_b, float* __restrict__ out)
{
    const int b = blockIdx.x;
    const int t = threadIdx.x;
    __shared__ __align__(16) float xin[16][INW];
    __shared__ __align__(16) float xwl[16][G4];
    __shared__ __align__(16) float h_s[HID];
    __shared__ __align__(16) float g_s[G4];
    float wih[INW]; float whh[HID];
    float bias = 0.f, K = 0.f, Aa = 0.f, Bb = 0.f;
    if (t < G4) {
        const float4* wr = (const float4*)(W_ih + t * INW);
        #pragma unroll
        for (int i = 0; i < INW/4; ++i) { float4 v = wr[i]; wih[4*i]=v.x; wih[4*i+1]=v.y; wih[4*i+2]=v.z; wih[4*i+3]=v.w; }
        const float4* hr = (const float4*)(W_hh + t * HID);
        #pragma unroll
        for (int j = 0; j < HID/4; ++j) { float4 v = hr[j]; whh[4*j]=v.x; whh[4*j+1]=v.y; whh[4*j+2]=v.z; whh[4*j+3]=v.w; }
        bias = b_ih[t] + b_hh[t];
        const bool tnh = (t >= 2*HID && t < 3*HID);
        K  = tnh ?  2.8853900817779268f : -1.4426950408889634f;
        Aa = tnh ?  1.f : 0.f;
        Bb = tnh ? -2.f : 1.f;
    }
    float c = 0.f;
    if (t < HID) { c = c0[b*HID + t]; h_s[t] = h0[b*HID + t]; }
    __syncthreads();
    const float* xb = x + (size_t)b * 4 * TT;
    for (int ck = 0; ck < SS/16; ++ck) {
        const int base = ck * 16 * UNIT;
        for (int j = t; j < 4*16*UNIT; j += 192) {
            int chn = j / (16*UNIT); int r = j - chn*(16*UNIT);
            xin[r/UNIT][chn*UNIT + (r%UNIT)] = xb[chn*TT + base + r];
        }
        __syncthreads();
        if (t < G4) {
            for (int s = 0; s < 16; ++s) {
                const float4* xv = (const float4*)xin[s];
                float a0 = bias, a1 = 0.f, a2 = 0.f, a3 = 0.f;
                #pragma unroll
                for (int i = 0; i < INW/4; ++i) {
                    float4 v = xv[i];
                    a0 += v.x*wih[4*i]; a1 += v.y*wih[4*i+1]; a2 += v.z*wih[4*i+2]; a3 += v.w*wih[4*i+3];
                }
                xwl[s][t] = (a0+a1)+(a2+a3);
            }
        }
        __syncthreads();
        for (int s = 0; s < 16; ++s) {
            if (t < G4) {
                const float4* hv = (const float4*)h_s;
                float a0 = xwl[s][t], a1 = 0.f, a2 = 0.f, a3 = 0.f;
                #pragma unroll
                for (int j = 0; j < HID/4; ++j) {
                    float4 v = hv[j];
                    a0 += v.x*whh[4*j]; a1 += v.y*whh[4*j+1]; a2 += v.z*whh[4*j+2]; a3 += v.w*whh[4*j+3];
                }
                float acc = (a0+a1)+(a2+a3);
                g_s[t] = Aa + Bb * rcp_hw(1.f + exp2_hw(K * acc));
            }
            __syncthreads();
            if (t < HID) {
                float ig=g_s[t], fg=g_s[HID+t], gg=g_s[2*HID+t], og=g_s[3*HID+t];
                c = fg*c + ig*gg;
                h_s[t] = og * tanh_hw(c);
            }
            __syncthreads();
        }
    }
    if (t < 16) {
        float a = fc1_b[t];
        #pragma unroll
        for (int j = 0; j < HID; ++j) a += h_s[j]*fc1_w[t*HID+j];
        g_s[t] = fmaxf(a, 0.f);
    }
    __syncthreads();
    if (t < NCLS) {
        float a = fc2_b[t];
        #pragma unroll
        for (int j = 0; j < 16; ++j) a += g_s[j]*fc2_w[t*16+j];
        out[b*NCLS + t] = a;
    }
}

extern "C" void kernel_launch(void* const* d_in, const int* in_sizes, int n_in,
                              void* d_out, int out_size, void* d_ws, size_t ws_size,
                              hipStream_t stream) {
    const float* x     = (const float*)d_in[0];
    const float* h0    = (const float*)d_in[1];
    const float* c0    = (const float*)d_in[2];
    const float* W_ih  = (const float*)d_in[3];
    const float* W_hh  = (const float*)d_in[4];
    const float* b_ih  = (const float*)d_in[5];
    const float* b_hh  = (const float*)d_in[6];
    const float* fc1_w = (const float*)d_in[7];
    const float* fc1_b = (const float*)d_in[8];
    const float* fc2_w = (const float*)d_in[9];
    const float* fc2_b = (const float*)d_in[10];
    float* out = (float*)d_out;

    // ---- primary path: full-sequence xw (+PAD slop) in workspace ----
    const size_t need = 4ull * ((size_t)(SS + PAD) * BB * G4);
    if (ws_size >= need) {
        float* xwbuf = (float*)d_ws;
        lstm_proj2<<<BB * (SS/128), 192, 0, stream>>>(x, W_ih, b_ih, b_hh,
                                                      xwbuf, 0, SS, SS/128);
        lstm_recur_full<<<BB / 4, 256, 0, stream>>>(xwbuf, h0, c0, W_hh,
                                                    fc1_w, fc1_b, fc2_w, fc2_b, out);
        return;
    }

    // ---- fallback: chunked path ----
    const size_t state_floats = (size_t)BB * HID * 2;
    long cap = (long)(ws_size / 4) - (long)state_floats;
    long sc  = (cap > 0) ? cap / ((long)BB * G4) : 0;
    int  SC  = (int)((sc > SS) ? SS : sc) & ~15;

    if (SC < 16) {
        lstm_fused<<<BB, 192, 0, stream>>>(x, h0, c0, W_ih, W_hh, b_ih, b_hh,
                                           fc1_w, fc1_b, fc2_w, fc2_b, out);
        return;
    }

    float* state = (float*)d_ws;
    float* xwbuf = state + state_floats;

    for (int s0 = 0; s0 < SS; s0 += SC) {
        int cnt = SS - s0; if (cnt > SC) cnt = SC;
        int nseq = (cnt + 127) / 128;
        lstm_proj2<<<BB * nseq, 192, 0, stream>>>(x, W_ih, b_ih, b_hh, xwbuf, s0, cnt, nseq);
        lstm_recur<<<BB / 4, 256, 0, stream>>>(xwbuf, h0, c0, W_hh,
                                               fc1_w, fc1_b, fc2_w, fc2_b,
                                               state, out, s0, cnt);
    }
}